// Round 16
// baseline (107.680 us; speedup 1.0000x reference)
//
#include <hip/hip_runtime.h>
#include <hip/hip_fp16.h>

#define SEQ   80
#define BATCH 32768
#define HID   10

typedef unsigned int uint;
typedef unsigned short ushort;
typedef _Float16 f16;
typedef __attribute__((ext_vector_type(8))) _Float16 f16x8;
typedef __attribute__((ext_vector_type(2))) _Float16 f16x2;
typedef __attribute__((ext_vector_type(2))) __fp16 fp16x2;
typedef __attribute__((ext_vector_type(4))) float f32x4;

#define SIG_SCALE  (-1.44269504f)
#define TANH_SCALE (-2.88539008f)

__device__ __forceinline__ float fast_rcp(float x)  { return __builtin_amdgcn_rcpf(x); }
__device__ __forceinline__ float fast_exp2(float x) { return __builtin_amdgcn_exp2f(x); }
__device__ __forceinline__ float sigp(float a)  { return fast_rcp(1.0f + fast_exp2(a)); }
__device__ __forceinline__ float tanhp(float a) { return 2.0f * fast_rcp(1.0f + fast_exp2(a)) - 1.0f; }
__device__ __forceinline__ float tanh_f(float x){ return tanhp(TANH_SCALE * x); }

union U4V { uint4 u; f16x8 v; };
union UH2 { uint u; f16x2 h; fp16x2 p; };
union HU  { f16 h; ushort s; };

// Single-rcp-merged LSTM cell: 5 exp2 + 2 rcp = 7 trans.
__device__ __forceinline__ float lstm_unit(const f32x4 d, float& c) {
    const float Ei = fast_exp2(d[0]);
    const float Ef = fast_exp2(d[1]);
    const float Eg = fast_exp2(d[2]);
    const float Eo = fast_exp2(d[3]);
    const float Pi = 1.0f + Ei, Pf = 1.0f + Ef, Pg = 1.0f + Eg;
    const float PiPg = Pi * Pg;
    const float R = fast_rcp(PiPg * Pf);
    c = c * (PiPg * R) + ((1.0f - Eg) * Pf) * R;
    const float Ec = fast_exp2(TANH_SCALE * c);
    const float R2 = fast_rcp((1.0f + Eo) * (1.0f + Ec));
    return (1.0f - Ec) * R2;
}

// Unified-B LSTM, TWO independent batch-16 groups per wave (intra-wave ILP).
// r15 showed ~50% issue duty at 2 waves/SIMD and r12 showed more TLP doesn't
// lift it: in-order waves expose each step's serial chain (ds_read -> MFMA ->
// 7-deep trans -> ds_write). A second independent group in the SAME wave
// gives the scheduler 2x independent chains to fill the bubbles. A-fragments
// and biases are shared between the groups (same weights) so register cost
// stays moderate. 1024 waves, no barriers.
__global__ __launch_bounds__(256, 1)
void lstm2_uni2(const float* __restrict__ x, const float* __restrict__ h0in,
                const float* __restrict__ c0in,
                const float* __restrict__ Wih0, const float* __restrict__ Whh0,
                const float* __restrict__ bih0, const float* __restrict__ bhh0,
                const float* __restrict__ Wih1, const float* __restrict__ Whh1,
                const float* __restrict__ bih1, const float* __restrict__ bhh1,
                ushort* __restrict__ y /* f16 bits of h1 (pre-tanh), [T,B,H] */) {
    __shared__ __align__(16) ushort buf[4][2][16][40];
    const int tid = threadIdx.x;
    const int l   = tid & 63;
    const int wv  = tid >> 6;
    ushort (*B0)[40] = buf[wv][0];
    ushort (*B1)[40] = buf[wv][1];
    const int bl  = l & 15;     // batch column
    const int grp = l >> 4;     // k/row group
    const long g0 = ((long)blockIdx.x * 4 + wv) * 2;        // group index pair
    const long b0 = g0 * 16 + bl;
    const long b1 = b0 + 16;

    // ---------- A fragments (5 tiles, 80 rows) + bias — SHARED by groups ----------
    f16x8 A[5];
    f32x4 bs[5];
#pragma unroll
    for (int T = 0; T < 5; ++T) {
        const int R = 16 * T + bl;              // A row 0..79
        const bool isL0 = (R < 40);
        const int rr = isL0 ? R : R - 40;
        const int u  = rr >> 2, gi = rr & 3;
        const int tr = gi * 10 + u;             // torch row (i|f|g|o chunks)
        const float sc = (gi == 2) ? TANH_SCALE : SIG_SCALE;
#pragma unroll
        for (int j = 0; j < 8; ++j) {
            const int k = grp * 8 + j;
            float w = 0.f;
            if (isL0) {
                if (k < 10)                  w = Whh0[tr * 10 + k];
                else if (k == 20 || k == 21) w = Wih0[tr * 2 + (k - 20)];
            } else {
                if (k < 10)      w = Wih1[tr * 10 + k];
                else if (k < 20) w = Whh1[tr * 10 + (k - 10)];
            }
            A[T][j] = (f16)(w * sc);
        }
#pragma unroll
        for (int q = 0; q < 4; ++q) {
            const int Rc = 16 * T + grp * 4 + q;
            const bool l0r = (Rc < 40);
            const int rc = l0r ? Rc : Rc - 40;
            const int uc = rc >> 2, gc = rc & 3;
            const float scc = (gc == 2) ? TANH_SCALE : SIG_SCALE;
            const int trc = gc * 10 + uc;
            bs[T][q] = (l0r ? (bih0[trc] + bhh0[trc]) : (bih1[trc] + bhh1[trc])) * scc;
        }
    }

    // ---------- per-group c state ----------
    float cS[2][5];
#pragma unroll
    for (int T = 0; T < 5; ++T) {
        const int up = 4 * T + grp;
        cS[0][T] = (up < 10) ? c0in[b0 * 10 + up]
                             : c0in[(size_t)BATCH * 10 + b0 * 10 + (up - 10)];
        cS[1][T] = (up < 10) ? c0in[b1 * 10 + up]
                             : c0in[(size_t)BATCH * 10 + b1 * 10 + (up - 10)];
    }

    // ---------- LDS init: zero my wave region, seed h and x(0) ----------
    {
        uint* p = (uint*)buf[wv];                // 2*16*40*2B = 2560B = 640 uints
#pragma unroll
        for (int i = 0; i < 10; ++i) p[l * 10 + i] = 0u;
    }
#pragma unroll
    for (int T = 0; T < 5; ++T) {
        const int up = 4 * T + grp;
        HU ha, hb;
        ha.h = (up < 10) ? (f16)h0in[b0 * 10 + up]
                         : (f16)h0in[(size_t)BATCH * 10 + b0 * 10 + (up - 10)];
        hb.h = (up < 10) ? (f16)h0in[b1 * 10 + up]
                         : (f16)h0in[(size_t)BATCH * 10 + b1 * 10 + (up - 10)];
        B0[bl][up] = ha.s;
        B1[bl][up] = hb.s;
    }
    {
        const float2 xa = *reinterpret_cast<const float2*>(x + b0 * 2);
        const float2 xb = *reinterpret_cast<const float2*>(x + b1 * 2);
        UH2 pa; pa.p = __builtin_amdgcn_cvt_pkrtz(xa.x, xa.y);
        UH2 pb; pb.p = __builtin_amdgcn_cvt_pkrtz(xb.x, xb.y);
        if (grp == 0) { *(uint*)&B0[bl][20] = pa.u; *(uint*)&B1[bl][20] = pb.u; }
    }

    const float* xq0 = x + (size_t)BATCH * 2 + b0 * 2;   // x(1)
    const float* xq1 = x + (size_t)BATCH * 2 + b1 * 2;
    ushort* yq0 = y + b0 * HID;
    ushort* yq1 = y + b1 * HID;

    for (int i = 0; i <= SEQ; ++i) {
        const bool doL0 = (i < SEQ);
        const bool doL1 = (i >= 1);
        const bool p2   = (grp < 2) ? doL0 : doL1;

        // both unified-B reads + both x prefetches up front
        U4V r0; r0.u = *reinterpret_cast<const uint4*>(&B0[bl][0] + grp * 8);
        U4V r1; r1.u = *reinterpret_cast<const uint4*>(&B1[bl][0] + grp * 8);
        const float2 xn0 = *reinterpret_cast<const float2*>(xq0);
        const float2 xn1 = *reinterpret_cast<const float2*>(xq1);

        // 10 MFMA on shared A/bs
        const f32x4 da0 = __builtin_amdgcn_mfma_f32_16x16x32_f16(A[0], r0.v, bs[0], 0, 0, 0);
        const f32x4 db0 = __builtin_amdgcn_mfma_f32_16x16x32_f16(A[0], r1.v, bs[0], 0, 0, 0);
        const f32x4 da1 = __builtin_amdgcn_mfma_f32_16x16x32_f16(A[1], r0.v, bs[1], 0, 0, 0);
        const f32x4 db1 = __builtin_amdgcn_mfma_f32_16x16x32_f16(A[1], r1.v, bs[1], 0, 0, 0);
        const f32x4 da2 = __builtin_amdgcn_mfma_f32_16x16x32_f16(A[2], r0.v, bs[2], 0, 0, 0);
        const f32x4 db2 = __builtin_amdgcn_mfma_f32_16x16x32_f16(A[2], r1.v, bs[2], 0, 0, 0);
        const f32x4 da3 = __builtin_amdgcn_mfma_f32_16x16x32_f16(A[3], r0.v, bs[3], 0, 0, 0);
        const f32x4 db3 = __builtin_amdgcn_mfma_f32_16x16x32_f16(A[3], r1.v, bs[3], 0, 0, 0);
        const f32x4 da4 = __builtin_amdgcn_mfma_f32_16x16x32_f16(A[4], r0.v, bs[4], 0, 0, 0);
        const f32x4 db4 = __builtin_amdgcn_mfma_f32_16x16x32_f16(A[4], r1.v, bs[4], 0, 0, 0);

        // 10 independent lstm_unit chains
        float ca0 = cS[0][0], ca1 = cS[0][1], ca2 = cS[0][2], ca3 = cS[0][3], ca4 = cS[0][4];
        float cb0 = cS[1][0], cb1 = cS[1][1], cb2 = cS[1][2], cb3 = cS[1][3], cb4 = cS[1][4];
        HU ha0; ha0.h = (f16)lstm_unit(da0, ca0);
        HU hb0; hb0.h = (f16)lstm_unit(db0, cb0);
        HU ha1; ha1.h = (f16)lstm_unit(da1, ca1);
        HU hb1; hb1.h = (f16)lstm_unit(db1, cb1);
        HU ha2; ha2.h = (f16)lstm_unit(da2, ca2);
        HU hb2; hb2.h = (f16)lstm_unit(db2, cb2);
        HU ha3; ha3.h = (f16)lstm_unit(da3, ca3);
        HU hb3; hb3.h = (f16)lstm_unit(db3, cb3);
        HU ha4; ha4.h = (f16)lstm_unit(da4, ca4);
        HU hb4; hb4.h = (f16)lstm_unit(db4, cb4);
        cS[0][0] = doL0 ? ca0 : cS[0][0];
        cS[0][1] = doL0 ? ca1 : cS[0][1];
        cS[0][2] = p2   ? ca2 : cS[0][2];
        cS[0][3] = doL1 ? ca3 : cS[0][3];
        cS[0][4] = doL1 ? ca4 : cS[0][4];
        cS[1][0] = doL0 ? cb0 : cS[1][0];
        cS[1][1] = doL0 ? cb1 : cS[1][1];
        cS[1][2] = p2   ? cb2 : cS[1][2];
        cS[1][3] = doL1 ? cb3 : cS[1][3];
        cS[1][4] = doL1 ? cb4 : cS[1][4];

        // h publish (slot = unit id)
        ushort* ra = &B0[bl][0];
        ushort* rb = &B1[bl][0];
        if (doL0) { ra[grp] = ha0.s; ra[4 + grp] = ha1.s;
                    rb[grp] = hb0.s; rb[4 + grp] = hb1.s; }
        if (p2)   { ra[8 + grp] = ha2.s; rb[8 + grp] = hb2.s; }
        if (doL1) { ra[12 + grp] = ha3.s; ra[16 + grp] = ha4.s;
                    rb[12 + grp] = hb3.s; rb[16 + grp] = hb4.s; }

        // x(i+1) into slots 20,21
        {
            UH2 pa; pa.p = __builtin_amdgcn_cvt_pkrtz(xn0.x, xn0.y);
            UH2 pb; pb.p = __builtin_amdgcn_cvt_pkrtz(xn1.x, xn1.y);
            if (grp == 0) { *(uint*)&B0[bl][20] = pa.u; *(uint*)&B1[bl][20] = pb.u; }
        }

        // y stores: raw h1 f16 bits (tanh in head)
        if (doL1) {
            if (grp >= 2) { yq0[grp - 2] = ha2.s; yq1[grp - 2] = hb2.s; }
            yq0[2 + grp] = ha3.s; yq0[6 + grp] = ha4.s;
            yq1[2 + grp] = hb3.s; yq1[6 + grp] = hb4.s;
            yq0 += (size_t)BATCH * HID;
            yq1 += (size_t)BATCH * HID;
        }

        if (i < SEQ - 2) { xq0 += (size_t)BATCH * 2; xq1 += (size_t)BATCH * 2; }
    }
}

// Head as MFMA GEMM over tanh(y), k-split across 2 waves per 16-row group —
// round-12 version verbatim (measured ~8 us).
__global__ __launch_bounds__(256, 2)
void head_mfma(const ushort* __restrict__ yflat, /* f16 bits of h1, [32768][800] */
               const float* __restrict__ W1, const float* __restrict__ b1,
               const float* __restrict__ W2, const float* __restrict__ b2,
               float* __restrict__ out) {
    __shared__ float sbuf[2][2][16][12];
    const int tid  = threadIdx.x;
    const int l    = tid & 63;
    const int wv   = tid >> 6;
    const int rg   = wv >> 1;      // row group 0,1
    const int half = wv & 1;       // k half 0,1
    const int bl   = l & 15;
    const int grp  = l >> 4;
    const long row = ((long)blockIdx.x * 2 + rg) * 16 + bl;

    const ushort* yrow = yflat + row * 800;
    const float* arow = W1 + (size_t)(bl < 10 ? bl : 9) * 800;

    const int c0 = half ? 13 : 0;
    const int c1 = half ? 25 : 13;

    f32x4 acc = {0.f, 0.f, 0.f, 0.f};
    for (int c = c0; c < c1; ++c) {
        U4V bv; bv.u = *reinterpret_cast<const uint4*>(yrow + c * 32 + grp * 8);
        f16x8 tv;
#pragma unroll
        for (int e = 0; e < 8; ++e)
            tv[e] = (f16)tanh_f((float)bv.v[e]);
        const float4 w0 = *reinterpret_cast<const float4*>(arow + c * 32 + grp * 8);
        const float4 w1 = *reinterpret_cast<const float4*>(arow + c * 32 + grp * 8 + 4);
        f16x8 af;
        af[0] = (f16)w0.x; af[1] = (f16)w0.y; af[2] = (f16)w0.z; af[3] = (f16)w0.w;
        af[4] = (f16)w1.x; af[5] = (f16)w1.y; af[6] = (f16)w1.z; af[7] = (f16)w1.w;
        acc = __builtin_amdgcn_mfma_f32_16x16x32_f16(af, tv, acc, 0, 0, 0);
    }

#pragma unroll
    for (int q = 0; q < 4; ++q) {
        const int o = grp * 4 + q;
        if (o < 10)
            sbuf[rg][half][bl][o] = acc[q];
    }
    __syncthreads();

    float s[10];
#pragma unroll
    for (int o = 0; o < 10; ++o)
        s[o] = sigp(SIG_SCALE * (sbuf[rg][0][bl][o] + sbuf[rg][1][bl][o] + b1[o]));

    const int jbase = half * 20 + (grp & 1) * 10;
    float* op = out + row * 40 + jbase;
#pragma unroll
    for (int jj = 0; jj < 10; ++jj) {
        const int j = jbase + jj;
        float r = b2[j];
#pragma unroll
        for (int o = 0; o < 10; ++o) r += s[o] * W2[j * 10 + o];
        op[jj] = r;
    }
}

extern "C" void kernel_launch(void* const* d_in, const int* in_sizes, int n_in,
                              void* d_out, int out_size, void* d_ws, size_t ws_size,
                              hipStream_t stream) {
    const float* x    = (const float*)d_in[0];
    const float* h0   = (const float*)d_in[1];
    const float* c0   = (const float*)d_in[2];
    const float* Wih0 = (const float*)d_in[3];
    const float* Whh0 = (const float*)d_in[4];
    const float* bih0 = (const float*)d_in[5];
    const float* bhh0 = (const float*)d_in[6];
    const float* Wih1 = (const float*)d_in[7];
    const float* Whh1 = (const float*)d_in[8];
    const float* bih1 = (const float*)d_in[9];
    const float* bhh1 = (const float*)d_in[10];
    const float* W1   = (const float*)d_in[11];
    const float* b1   = (const float*)d_in[12];
    const float* W2   = (const float*)d_in[13];
    const float* b2   = (const float*)d_in[14];
    float* out = (float*)d_out;
    ushort* yws = (ushort*)d_ws;  // f16 staging (raw h1), 80*32768*10*2 B

    // 2 batch-16 groups per wave, 4 waves per block: 32768/(32*4) = 256 blocks
    lstm2_uni2<<<256, 256, 0, stream>>>(x, h0, c0, Wih0, Whh0, bih0, bhh0,
                                        Wih1, Whh1, bih1, bhh1, yws);
    // 2 row-groups x 2 k-half waves per 256-thread block: 1024 blocks
    head_mfma<<<1024, 256, 0, stream>>>(yws, W1, b1, W2, b2, out);
}

// Round 17
// 87.610 us; speedup vs baseline: 1.2291x; 1.2291x over previous
//
#include <hip/hip_runtime.h>
#include <hip/hip_fp16.h>

#define SEQ   80
#define BATCH 32768
#define HID   10

typedef unsigned int uint;
typedef unsigned short ushort;
typedef _Float16 f16;
typedef __attribute__((ext_vector_type(8))) _Float16 f16x8;
typedef __attribute__((ext_vector_type(2))) _Float16 f16x2;
typedef __attribute__((ext_vector_type(2))) __fp16 fp16x2;
typedef __attribute__((ext_vector_type(4))) float f32x4;

#define SIG_SCALE  (-1.44269504f)
#define TANH_SCALE (-2.88539008f)

__device__ __forceinline__ float fast_rcp(float x)  { return __builtin_amdgcn_rcpf(x); }
__device__ __forceinline__ float fast_exp2(float x) { return __builtin_amdgcn_exp2f(x); }
__device__ __forceinline__ float sigp(float a)  { return fast_rcp(1.0f + fast_exp2(a)); }
__device__ __forceinline__ float tanhp(float a) { return 2.0f * fast_rcp(1.0f + fast_exp2(a)) - 1.0f; }
__device__ __forceinline__ float tanh_f(float x){ return tanhp(TANH_SCALE * x); }

union U4V { uint4 u; f16x8 v; };
union UH2 { uint u; f16x2 h; fp16x2 p; };
union HU  { f16 h; ushort s; };

// Single-rcp-merged LSTM cell: 5 exp2 + 2 rcp = 7 trans.
__device__ __forceinline__ float lstm_unit(const f32x4 d, float& c) {
    const float Ei = fast_exp2(d[0]);
    const float Ef = fast_exp2(d[1]);
    const float Eg = fast_exp2(d[2]);
    const float Eo = fast_exp2(d[3]);
    const float Pi = 1.0f + Ei, Pf = 1.0f + Ef, Pg = 1.0f + Eg;
    const float PiPg = Pi * Pg;
    const float R = fast_rcp(PiPg * Pf);
    c = c * (PiPg * R) + ((1.0f - Eg) * Pf) * R;
    const float Ec = fast_exp2(TANH_SCALE * c);
    const float R2 = fast_rcp((1.0f + Eo) * (1.0f + Ec));
    return (1.0f - Ec) * R2;
}

// Unified-B single-wave LSTM (r15 structure = best measured, 76.5 us) with
// boundary iterations PEELED: i=0 (L0 only) and i=80 (L1 only) explicit, so
// the 79-iteration main loop is straight-line — no doL0/doL1/p2 predicates,
// no cndmask commits, unconditional stores.
__global__ __launch_bounds__(256, 2)
void lstm2_uni(const float* __restrict__ x, const float* __restrict__ h0in,
               const float* __restrict__ c0in,
               const float* __restrict__ Wih0, const float* __restrict__ Whh0,
               const float* __restrict__ bih0, const float* __restrict__ bhh0,
               const float* __restrict__ Wih1, const float* __restrict__ Whh1,
               const float* __restrict__ bih1, const float* __restrict__ bhh1,
               ushort* __restrict__ y /* f16 bits of h1 (pre-tanh), [T,B,H] */) {
    __shared__ __align__(16) ushort buf[4][16][40];
    const int tid = threadIdx.x;
    const int l   = tid & 63;
    const int wv  = tid >> 6;
    ushort (*B)[40] = buf[wv];
    const int bl  = l & 15;     // batch column
    const int grp = l >> 4;     // k/row group
    const long b  = ((long)blockIdx.x * 4 + wv) * 16 + bl;

    // ---------- A fragments (5 tiles, 80 rows), bias, c ----------
    f16x8 A[5];
    f32x4 bs[5];
    float cS[5];
#pragma unroll
    for (int T = 0; T < 5; ++T) {
        const int R = 16 * T + bl;              // A row 0..79
        const bool isL0 = (R < 40);
        const int rr = isL0 ? R : R - 40;
        const int u  = rr >> 2, gi = rr & 3;
        const int tr = gi * 10 + u;             // torch row (i|f|g|o chunks)
        const float sc = (gi == 2) ? TANH_SCALE : SIG_SCALE;
#pragma unroll
        for (int j = 0; j < 8; ++j) {
            const int k = grp * 8 + j;
            float w = 0.f;
            if (isL0) {
                if (k < 10)                  w = Whh0[tr * 10 + k];
                else if (k == 20 || k == 21) w = Wih0[tr * 2 + (k - 20)];
            } else {
                if (k < 10)      w = Wih1[tr * 10 + k];
                else if (k < 20) w = Whh1[tr * 10 + (k - 10)];
            }
            A[T][j] = (f16)(w * sc);
        }
#pragma unroll
        for (int q = 0; q < 4; ++q) {
            const int Rc = 16 * T + grp * 4 + q;   // D row this lane holds
            const bool l0 = (Rc < 40);
            const int rc = l0 ? Rc : Rc - 40;
            const int uc = rc >> 2, gc = rc & 3;
            const float scc = (gc == 2) ? TANH_SCALE : SIG_SCALE;
            const int trc = gc * 10 + uc;
            bs[T][q] = (l0 ? (bih0[trc] + bhh0[trc]) : (bih1[trc] + bhh1[trc])) * scc;
        }
        const int up = 4 * T + grp;             // this lane's unit id 0..19
        cS[T] = (up < 10) ? c0in[b * 10 + up]
                          : c0in[(size_t)BATCH * 10 + b * 10 + (up - 10)];
    }

    // ---------- LDS init: zero row tail, seed h0/h1/x(0) ----------
    {
        uint* p = (uint*)B;                      // 320 uints per group
#pragma unroll
        for (int i = 0; i < 5; ++i) p[l * 5 + i] = 0u;
    }
#pragma unroll
    for (int T = 0; T < 5; ++T) {
        const int up = 4 * T + grp;
        HU h;
        h.h = (up < 10) ? (f16)h0in[b * 10 + up]
                        : (f16)h0in[(size_t)BATCH * 10 + b * 10 + (up - 10)];
        B[bl][up] = h.s;
    }
    {
        const float2 x0 = *reinterpret_cast<const float2*>(x + b * 2);
        UH2 xp; xp.p = __builtin_amdgcn_cvt_pkrtz(x0.x, x0.y);
        if (grp == 0) *(uint*)&B[bl][20] = xp.u;
    }

    const float* xq = x + (size_t)BATCH * 2 + b * 2;   // x(1)
    ushort* yq = y + b * HID;                           // y(0) base

    // ================= i = 0: layer 0 only =================
    {
        U4V r; r.u = *reinterpret_cast<const uint4*>(&B[bl][0] + grp * 8);
        const float2 xnext = *reinterpret_cast<const float2*>(xq);

        const f32x4 d0 = __builtin_amdgcn_mfma_f32_16x16x32_f16(A[0], r.v, bs[0], 0, 0, 0);
        const f32x4 d1 = __builtin_amdgcn_mfma_f32_16x16x32_f16(A[1], r.v, bs[1], 0, 0, 0);
        const f32x4 d2 = __builtin_amdgcn_mfma_f32_16x16x32_f16(A[2], r.v, bs[2], 0, 0, 0);

        float c2n = cS[2];
        HU h0v; h0v.h = (f16)lstm_unit(d0, cS[0]);
        HU h1v; h1v.h = (f16)lstm_unit(d1, cS[1]);
        HU h2v; h2v.h = (f16)lstm_unit(d2, c2n);
        cS[2] = (grp < 2) ? c2n : cS[2];

        ushort* row = &B[bl][0];
        row[grp] = h0v.s;
        row[4 + grp] = h1v.s;
        if (grp < 2) row[8 + grp] = h2v.s;

        UH2 xp; xp.p = __builtin_amdgcn_cvt_pkrtz(xnext.x, xnext.y);
        if (grp == 0) *(uint*)&B[bl][20] = xp.u;

        xq += (size_t)BATCH * 2;
    }

    // ================= main loop i = 1..79: straight-line =================
    for (int i = 1; i < SEQ; ++i) {
        U4V r; r.u = *reinterpret_cast<const uint4*>(&B[bl][0] + grp * 8);
        const float2 xnext = *reinterpret_cast<const float2*>(xq);

        const f32x4 d0 = __builtin_amdgcn_mfma_f32_16x16x32_f16(A[0], r.v, bs[0], 0, 0, 0);
        const f32x4 d1 = __builtin_amdgcn_mfma_f32_16x16x32_f16(A[1], r.v, bs[1], 0, 0, 0);
        const f32x4 d2 = __builtin_amdgcn_mfma_f32_16x16x32_f16(A[2], r.v, bs[2], 0, 0, 0);
        const f32x4 d3 = __builtin_amdgcn_mfma_f32_16x16x32_f16(A[3], r.v, bs[3], 0, 0, 0);
        const f32x4 d4 = __builtin_amdgcn_mfma_f32_16x16x32_f16(A[4], r.v, bs[4], 0, 0, 0);

        HU h0v; h0v.h = (f16)lstm_unit(d0, cS[0]);
        HU h1v; h1v.h = (f16)lstm_unit(d1, cS[1]);
        HU h2v; h2v.h = (f16)lstm_unit(d2, cS[2]);
        HU h3v; h3v.h = (f16)lstm_unit(d3, cS[3]);
        HU h4v; h4v.h = (f16)lstm_unit(d4, cS[4]);

        ushort* row = &B[bl][0];
        row[grp]      = h0v.s;
        row[4 + grp]  = h1v.s;
        row[8 + grp]  = h2v.s;
        row[12 + grp] = h3v.s;
        row[16 + grp] = h4v.s;

        UH2 xp; xp.p = __builtin_amdgcn_cvt_pkrtz(xnext.x, xnext.y);
        if (grp == 0) *(uint*)&B[bl][20] = xp.u;

        if (grp >= 2) yq[grp - 2] = h2v.s;
        yq[2 + grp] = h3v.s;
        yq[6 + grp] = h4v.s;
        yq += (size_t)BATCH * HID;

        if (i < SEQ - 2) xq += (size_t)BATCH * 2;
    }

    // ================= i = 80: layer 1 only, y(79) =================
    {
        U4V r; r.u = *reinterpret_cast<const uint4*>(&B[bl][0] + grp * 8);

        const f32x4 d2 = __builtin_amdgcn_mfma_f32_16x16x32_f16(A[2], r.v, bs[2], 0, 0, 0);
        const f32x4 d3 = __builtin_amdgcn_mfma_f32_16x16x32_f16(A[3], r.v, bs[3], 0, 0, 0);
        const f32x4 d4 = __builtin_amdgcn_mfma_f32_16x16x32_f16(A[4], r.v, bs[4], 0, 0, 0);

        float c2n = cS[2], c3n = cS[3], c4n = cS[4];
        HU h2v; h2v.h = (f16)lstm_unit(d2, c2n);
        HU h3v; h3v.h = (f16)lstm_unit(d3, c3n);
        HU h4v; h4v.h = (f16)lstm_unit(d4, c4n);

        if (grp >= 2) yq[grp - 2] = h2v.s;
        yq[2 + grp] = h3v.s;
        yq[6 + grp] = h4v.s;
    }
}

// Head as MFMA GEMM over tanh(y), k-split across 2 waves per 16-row group —
// round-12 version verbatim (measured ~8 us, at its 52MB-read HBM floor).
__global__ __launch_bounds__(256, 2)
void head_mfma(const ushort* __restrict__ yflat, /* f16 bits of h1, [32768][800] */
               const float* __restrict__ W1, const float* __restrict__ b1,
               const float* __restrict__ W2, const float* __restrict__ b2,
               float* __restrict__ out) {
    __shared__ float sbuf[2][2][16][12];
    const int tid  = threadIdx.x;
    const int l    = tid & 63;
    const int wv   = tid >> 6;
    const int rg   = wv >> 1;      // row group 0,1
    const int half = wv & 1;       // k half 0,1
    const int bl   = l & 15;
    const int grp  = l >> 4;
    const long row = ((long)blockIdx.x * 2 + rg) * 16 + bl;

    const ushort* yrow = yflat + row * 800;
    const float* arow = W1 + (size_t)(bl < 10 ? bl : 9) * 800;

    const int c0 = half ? 13 : 0;
    const int c1 = half ? 25 : 13;

    f32x4 acc = {0.f, 0.f, 0.f, 0.f};
    for (int c = c0; c < c1; ++c) {
        U4V bv; bv.u = *reinterpret_cast<const uint4*>(yrow + c * 32 + grp * 8);
        f16x8 tv;
#pragma unroll
        for (int e = 0; e < 8; ++e)
            tv[e] = (f16)tanh_f((float)bv.v[e]);
        const float4 w0 = *reinterpret_cast<const float4*>(arow + c * 32 + grp * 8);
        const float4 w1 = *reinterpret_cast<const float4*>(arow + c * 32 + grp * 8 + 4);
        f16x8 af;
        af[0] = (f16)w0.x; af[1] = (f16)w0.y; af[2] = (f16)w0.z; af[3] = (f16)w0.w;
        af[4] = (f16)w1.x; af[5] = (f16)w1.y; af[6] = (f16)w1.z; af[7] = (f16)w1.w;
        acc = __builtin_amdgcn_mfma_f32_16x16x32_f16(af, tv, acc, 0, 0, 0);
    }

#pragma unroll
    for (int q = 0; q < 4; ++q) {
        const int o = grp * 4 + q;
        if (o < 10)
            sbuf[rg][half][bl][o] = acc[q];
    }
    __syncthreads();

    float s[10];
#pragma unroll
    for (int o = 0; o < 10; ++o)
        s[o] = sigp(SIG_SCALE * (sbuf[rg][0][bl][o] + sbuf[rg][1][bl][o] + b1[o]));

    const int jbase = half * 20 + (grp & 1) * 10;
    float* op = out + row * 40 + jbase;
#pragma unroll
    for (int jj = 0; jj < 10; ++jj) {
        const int j = jbase + jj;
        float r = b2[j];
#pragma unroll
        for (int o = 0; o < 10; ++o) r += s[o] * W2[j * 10 + o];
        op[jj] = r;
    }
}

extern "C" void kernel_launch(void* const* d_in, const int* in_sizes, int n_in,
                              void* d_out, int out_size, void* d_ws, size_t ws_size,
                              hipStream_t stream) {
    const float* x    = (const float*)d_in[0];
    const float* h0   = (const float*)d_in[1];
    const float* c0   = (const float*)d_in[2];
    const float* Wih0 = (const float*)d_in[3];
    const float* Whh0 = (const float*)d_in[4];
    const float* bih0 = (const float*)d_in[5];
    const float* bhh0 = (const float*)d_in[6];
    const float* Wih1 = (const float*)d_in[7];
    const float* Whh1 = (const float*)d_in[8];
    const float* bih1 = (const float*)d_in[9];
    const float* bhh1 = (const float*)d_in[10];
    const float* W1   = (const float*)d_in[11];
    const float* b1   = (const float*)d_in[12];
    const float* W2   = (const float*)d_in[13];
    const float* b2   = (const float*)d_in[14];
    float* out = (float*)d_out;
    ushort* yws = (ushort*)d_ws;  // f16 staging (raw h1), 80*32768*10*2 B

    // 4 batch-16 groups per 256-thread block (1 wave each, independent): 512 blocks
    lstm2_uni<<<512, 256, 0, stream>>>(x, h0, c0, Wih0, Whh0, bih0, bhh0,
                                       Wih1, Whh1, bih1, bhh1, yws);
    // 2 row-groups x 2 k-half waves per 256-thread block: 1024 blocks
    head_mfma<<<1024, 256, 0, stream>>>(yws, W1, b1, W2, b2, out);
}